// Round 11
// baseline (412.698 us; speedup 1.0000x reference)
//
#include <hip/hip_runtime.h>

#define NEG_SLOPE 0.2f
#define NB_SHIFT 8          // bucket = dst >> 8 (256-node windows)
#define LOG2E 1.4426950408889634f

typedef __attribute__((ext_vector_type(8))) short bf16x8;
typedef __attribute__((ext_vector_type(4))) float f32x4;

// bf16 helpers (RNE pack, cheap unpack)
__device__ inline unsigned f2bf(float f) {
    unsigned u = __float_as_uint(f);
    return (u + 0x7fffu + ((u >> 16) & 1u)) >> 16;
}
__device__ inline void bf8up(uint4 u, float* f) {
    f[0] = __uint_as_float(u.x << 16); f[1] = __uint_as_float(u.x & 0xffff0000u);
    f[2] = __uint_as_float(u.y << 16); f[3] = __uint_as_float(u.y & 0xffff0000u);
    f[4] = __uint_as_float(u.z << 16); f[5] = __uint_as_float(u.z & 0xffff0000u);
    f[6] = __uint_as_float(u.w << 16); f[7] = __uint_as_float(u.w & 0xffff0000u);
}
__device__ inline float exp2fast(float x) { return __builtin_amdgcn_exp2f(x); }

// ---------------- CSR build (no per-edge global atomics; packed pairs) ----------------

__global__ void zero_int_kernel(int* __restrict__ p, int n) {
    int i = blockIdx.x * blockDim.x + threadIdx.x;
    if (i < n) p[i] = 0;
}

__global__ __launch_bounds__(256) void bucket_count_kernel(const int* __restrict__ dst, int E,
                                                           int* __restrict__ bcnt, int NB) {
    __shared__ int cnt[512];
    for (int i = threadIdx.x; i < NB; i += 256) cnt[i] = 0;
    __syncthreads();
    int base = blockIdx.x * 16384;
    for (int k = 0; k < 64; ++k) {
        int i = base + k * 256 + threadIdx.x;
        if (i < E) atomicAdd(&cnt[dst[i] >> NB_SHIFT], 1);
    }
    __syncthreads();
    for (int i = threadIdx.x; i < NB; i += 256)
        if (cnt[i]) atomicAdd(&bcnt[i], cnt[i]);
}

__global__ __launch_bounds__(512) void scan_bucket_kernel(const int* __restrict__ bcnt, int nb,
                                                          int* __restrict__ bbase,
                                                          int* __restrict__ bcur,
                                                          int* __restrict__ rowptr, int N) {
    int t = threadIdx.x;
    int v = (t < nb) ? bcnt[t] : 0;
    int s = v;
    #pragma unroll
    for (int d = 1; d < 64; d <<= 1) {
        int o = __shfl_up(s, d);
        if ((t & 63) >= d) s += o;
    }
    __shared__ int ws[8];
    if ((t & 63) == 63) ws[t >> 6] = s;
    __syncthreads();
    int wid = t >> 6;
    int woff = 0;
    for (int w = 0; w < 8; ++w) woff += (w < wid) ? ws[w] : 0;
    int excl = s - v + woff;
    if (t < nb) { bbase[t] = excl; bcur[t] = excl; }
    if (t == 511) { bbase[nb] = excl + v; rowptr[N] = excl + v; }  // grand total = E
}

// scatter packed (src | dstlo<<24) into bucket-grouped storage; 8192 edges/block
__global__ __launch_bounds__(256) void bucket_scatter_kernel(const int* __restrict__ src,
                                                             const int* __restrict__ dst, int E,
                                                             int* __restrict__ bcur,
                                                             unsigned* __restrict__ pairs, int NB) {
    __shared__ int cnt[512];
    __shared__ int base_l[512];
    for (int i = threadIdx.x; i < NB; i += 256) cnt[i] = 0;
    __syncthreads();
    int tbase = blockIdx.x * 8192;
    unsigned e[32];
    int bk[32];
    int rk[32];
    #pragma unroll
    for (int k = 0; k < 32; ++k) {
        int i = tbase + k * 256 + threadIdx.x;
        if (i < E) {
            int dv = dst[i];
            e[k] = (unsigned)src[i] | ((unsigned)(dv & 255) << 24);
            bk[k] = dv >> NB_SHIFT;
            rk[k] = atomicAdd(&cnt[bk[k]], 1);
        } else {
            rk[k] = -1;
        }
    }
    __syncthreads();
    for (int i = threadIdx.x; i < NB; i += 256)
        base_l[i] = cnt[i] ? atomicAdd(&bcur[i], cnt[i]) : 0;
    __syncthreads();
    #pragma unroll
    for (int k = 0; k < 32; ++k)
        if (rk[k] >= 0) pairs[base_l[bk[k]] + rk[k]] = e[k];
}

__global__ __launch_bounds__(512) void build_csr_kernel(const unsigned* __restrict__ pairs,
                                                        const int* __restrict__ bbase,
                                                        int* __restrict__ rowptr,
                                                        int* __restrict__ csr, int N) {
    __shared__ int cnt[256];
    __shared__ int cur[256];
    __shared__ int ws[4];
    int b = blockIdx.x;
    int lo = bbase[b], hi = bbase[b + 1];
    int t = threadIdx.x;
    if (t < 256) cnt[t] = 0;
    __syncthreads();
    for (int j = lo + t; j < hi; j += 512)
        atomicAdd(&cnt[pairs[j] >> 24], 1);
    __syncthreads();
    int v = 0, s = 0;
    if (t < 256) {
        v = cnt[t];
        s = v;
        #pragma unroll
        for (int d = 1; d < 64; d <<= 1) {
            int o = __shfl_up(s, d);
            if ((t & 63) >= d) s += o;
        }
        if ((t & 63) == 63) ws[t >> 6] = s;
    }
    __syncthreads();
    if (t < 256) {
        int wid = t >> 6;
        int woff = 0;
        for (int w2 = 0; w2 < 4; ++w2) woff += (w2 < wid) ? ws[w2] : 0;
        int excl = lo + s - v + woff;
        int node = (b << NB_SHIFT) + t;
        if (node < N) rowptr[node] = excl;
        cur[t] = excl;
    }
    __syncthreads();
    for (int j = lo + t; j < hi; j += 512) {
        unsigned p = pairs[j];
        int pos = atomicAdd(&cur[p >> 24], 1);   // LDS atomic
        csr[pos] = (int)(p & 0x00FFFFFFu);
    }
}

// ---- GEMM1 (MFMA bf16): hb1 = bf16(x @ W1), fused as1/ad1 epilogue ----
// as1/ad1 pre-scaled by LOG2E (attention exps become bare exp2).

__global__ __launch_bounds__(512) void gemm1_kernel(const float* __restrict__ x,
                                                    const float* __restrict__ W,
                                                    const float* __restrict__ a_src,
                                                    const float* __restrict__ a_dst,
                                                    unsigned short* __restrict__ hb1,
                                                    float* __restrict__ as1,
                                                    float* __restrict__ ad1, int N) {
    __shared__ unsigned short Wl[16 * 4 * 64 * 8];   // 64 KB, fragment-ordered
    int tid = threadIdx.x;
    for (int i = tid; i < 512 * 16; i += 512) {
        int k = i >> 4, c4 = (i & 15) * 4;
        float4 v = *reinterpret_cast<const float4*>(&W[(size_t)k * 64 + c4]);
        int ks = k >> 5, kin = k & 31, g = kin >> 3, j = kin & 7;
        float vv[4] = {v.x, v.y, v.z, v.w};
        #pragma unroll
        for (int c = 0; c < 4; ++c) {
            int col = c4 + c;
            int nt = col >> 4, l16 = col & 15;
            Wl[(((ks * 4 + nt) * 64) + g * 16 + l16) * 8 + j] = (unsigned short)f2bf(vv[c]);
        }
    }
    __syncthreads();
    int wave = tid >> 6, lane = tid & 63;
    int m = lane & 15, g = lane >> 4;       // A-row within strip, k-group
    int row0 = blockIdx.x * 128 + wave * 16;
    int arow = row0 + m;
    bool aval = arow < N;
    const float* xr = x + (size_t)(aval ? arow : 0) * 512;
    float asw[4], adw[4];
    #pragma unroll
    for (int nt = 0; nt < 4; ++nt) {
        asw[nt] = a_src[nt * 16 + m] * LOG2E;
        adw[nt] = a_dst[nt * 16 + m] * LOG2E;
    }
    f32x4 acc[4] = {{0.f,0.f,0.f,0.f},{0.f,0.f,0.f,0.f},{0.f,0.f,0.f,0.f},{0.f,0.f,0.f,0.f}};
    for (int ks = 0; ks < 16; ++ks) {
        int ko = ks * 32 + g * 8;
        float4 u0 = make_float4(0.f, 0.f, 0.f, 0.f), u1 = u0;
        if (aval) {
            u0 = *reinterpret_cast<const float4*>(xr + ko);
            u1 = *reinterpret_cast<const float4*>(xr + ko + 4);
        }
        bf16x8 af;
        af[0] = (short)f2bf(u0.x); af[1] = (short)f2bf(u0.y);
        af[2] = (short)f2bf(u0.z); af[3] = (short)f2bf(u0.w);
        af[4] = (short)f2bf(u1.x); af[5] = (short)f2bf(u1.y);
        af[6] = (short)f2bf(u1.z); af[7] = (short)f2bf(u1.w);
        #pragma unroll
        for (int nt = 0; nt < 4; ++nt) {
            bf16x8 bf = *reinterpret_cast<const bf16x8*>(&Wl[((ks * 4 + nt) * 64 + lane) * 8]);
            acc[nt] = __builtin_amdgcn_mfma_f32_16x16x32_bf16(af, bf, acc[nt], 0, 0, 0);
        }
    }
    // D layout: col = lane&15 (=m), row = g*4 + reg  [verified m89]
    #pragma unroll
    for (int r = 0; r < 4; ++r) {
        int orow = row0 + g * 4 + r;
        if (orow < N) {
            #pragma unroll
            for (int nt = 0; nt < 4; ++nt) {
                float dv = acc[nt][r];
                hb1[(size_t)orow * 64 + nt * 16 + m] = (unsigned short)f2bf(dv);
                float pa = dv * asw[nt];
                float pd = dv * adw[nt];
                pa += __shfl_xor(pa, 1); pa += __shfl_xor(pa, 2); pa += __shfl_xor(pa, 4);
                pd += __shfl_xor(pd, 1); pd += __shfl_xor(pd, 2); pd += __shfl_xor(pd, 4);
                if ((m & 7) == 0) {
                    as1[orow * 8 + nt * 2 + (m >> 3)] = pa;
                    ad1[orow * 8 + nt * 2 + (m >> 3)] = pd;
                }
            }
        }
    }
}

// ---- layer-1 attention + FUSED gemm2/alpha2: fixed-reference softmax,
// 8 lanes/edge; epilogue computes h2 = ELU(out+b1) @ W2 in-wave, writes
// hb2 (bf16) + as2/ad2 directly. W2/a2 staged in LDS. ----

__global__ __launch_bounds__(256) void attn1_kernel(
    const unsigned short* __restrict__ hb1, const float* __restrict__ as1,
    const float* __restrict__ ad1, const int* __restrict__ rowptr,
    const int* __restrict__ csr_src, const float* __restrict__ b1,
    const float* __restrict__ W2, const float* __restrict__ a_src2,
    const float* __restrict__ a_dst2, unsigned short* __restrict__ hb2,
    float* __restrict__ as2, float* __restrict__ ad2, int N) {
    __shared__ float Ws[64 * 64];
    __shared__ float asw2[64], adw2[64];
    int tid = threadIdx.x;
    for (int i = tid; i < 64 * 64; i += 256) Ws[i] = W2[i];
    if (tid < 64) { asw2[tid] = a_src2[tid] * LOG2E; adw2[tid] = a_dst2[tid] * LOG2E; }
    __syncthreads();
    int wv = tid >> 6;
    int lane = tid & 63;
    int d = blockIdx.x * 4 + wv;
    if (d >= N) return;
    int beg = rowptr[d];
    int edeg = rowptr[d + 1] - beg;
    int tot = edeg + 1;  // + virtual self loop (src = d)
    int q8 = lane & 7, g = lane >> 3;
    float adh = ad1[d * 8 + q8];                  // log2-domain
    float es = as1[d * 8 + q8] + adh;             // self score (fixed softmax reference)
    es = fmaxf(es, NEG_SLOPE * es);
    const uint4* hb = reinterpret_cast<const uint4*>(hb1);
    float s = 0.f;
    float acc[8] = {0.f,0.f,0.f,0.f,0.f,0.f,0.f,0.f};
    for (int p0 = 0; p0 < tot; p0 += 8) {
        int p = p0 + g;
        int sn = (p < edeg) ? csr_src[beg + p] : d;
        float e = as1[sn * 8 + q8] + adh;
        e = fmaxf(e, NEG_SLOPE * e);
        float w = (p < tot) ? exp2fast(e - es) : 0.f;
        uint4 u = hb[(size_t)sn * 8 + q8];
        float f[8];
        bf8up(u, f);
        s += w;
        #pragma unroll
        for (int j = 0; j < 8; ++j) acc[j] = fmaf(w, f[j], acc[j]);
    }
    #pragma unroll
    for (int mask = 8; mask < 64; mask <<= 1) {
        s += __shfl_xor(s, mask);
        #pragma unroll
        for (int j = 0; j < 8; ++j) acc[j] += __shfl_xor(acc[j], mask);
    }
    // every lane now holds the reduced octet for head q8 (replicated over g)
    float inv = 1.f / (s + 1e-16f);
    const float4* b4 = reinterpret_cast<const float4*>(b1 + q8 * 8);
    float4 ba = b4[0], bb = b4[1];
    float o[8];
    o[0] = fmaf(acc[0], inv, ba.x); o[1] = fmaf(acc[1], inv, ba.y);
    o[2] = fmaf(acc[2], inv, ba.z); o[3] = fmaf(acc[3], inv, ba.w);
    o[4] = fmaf(acc[4], inv, bb.x); o[5] = fmaf(acc[5], inv, bb.y);
    o[6] = fmaf(acc[6], inv, bb.z); o[7] = fmaf(acc[7], inv, bb.w);
    #pragma unroll
    for (int j = 0; j < 8; ++j) o[j] = (o[j] > 0.f) ? o[j] : (__expf(o[j]) - 1.f);
    // fused gemm2: lane -> output dim `lane`; helu[c*8+i] = shfl(o[i], c)
    float h2v = 0.f;
    #pragma unroll
    for (int c = 0; c < 8; ++c) {
        #pragma unroll
        for (int i = 0; i < 8; ++i) {
            float hv = __shfl(o[i], c);
            h2v = fmaf(hv, Ws[(c * 8 + i) * 64 + lane], h2v);
        }
    }
    hb2[(size_t)d * 64 + lane] = (unsigned short)f2bf(h2v);
    float pa = h2v * asw2[lane];
    float pb = h2v * adw2[lane];
    #pragma unroll
    for (int mask = 1; mask < 64; mask <<= 1) {
        pa += __shfl_xor(pa, mask);
        pb += __shfl_xor(pb, mask);
    }
    if (lane == 0) { as2[d] = pa; ad2[d] = pb; }
}

// ---- layer-2 attention + log_softmax: fixed-reference softmax, 8 lanes/edge ----

__global__ __launch_bounds__(256) void attn2_kernel(
    const unsigned short* __restrict__ hb2, const float* __restrict__ as2,
    const float* __restrict__ ad2, const int* __restrict__ rowptr,
    const int* __restrict__ csr_src, const float* __restrict__ b2,
    float* __restrict__ out, int N) {
    int wv = threadIdx.x >> 6;
    int lane = threadIdx.x & 63;
    int d = blockIdx.x * 4 + wv;
    if (d >= N) return;
    int beg = rowptr[d];
    int edeg = rowptr[d + 1] - beg;
    int tot = edeg + 1;
    int q8 = lane & 7, g = lane >> 3;
    float add = ad2[d];                           // log2-domain
    float es = as2[d] + add;
    es = fmaxf(es, NEG_SLOPE * es);
    const uint4* hb = reinterpret_cast<const uint4*>(hb2);
    float s = 0.f;
    float acc[8] = {0.f,0.f,0.f,0.f,0.f,0.f,0.f,0.f};
    for (int p0 = 0; p0 < tot; p0 += 8) {
        int p = p0 + g;
        int sn = (p < edeg) ? csr_src[beg + p] : d;
        float e = as2[sn] + add;
        e = fmaxf(e, NEG_SLOPE * e);
        float w = (p < tot) ? exp2fast(e - es) : 0.f;
        uint4 u = hb[(size_t)sn * 8 + q8];
        float f[8];
        bf8up(u, f);
        s += w;
        #pragma unroll
        for (int j = 0; j < 8; ++j) acc[j] = fmaf(w, f[j], acc[j]);
    }
    #pragma unroll
    for (int mask = 8; mask < 64; mask <<= 1) {
        s += __shfl_xor(s, mask);
        #pragma unroll
        for (int j = 0; j < 8; ++j) acc[j] += __shfl_xor(acc[j], mask);
    }
    // all lanes hold full s / acc (xor-reduce broadcasts)
    float inv = 1.f / (s + 1e-16f);
    const float4* b4 = reinterpret_cast<const float4*>(b2 + q8 * 8);
    float4 ba = b4[0], bb = b4[1];
    float o[8];
    o[0] = fmaf(acc[0], inv, ba.x); o[1] = fmaf(acc[1], inv, ba.y);
    o[2] = fmaf(acc[2], inv, ba.z); o[3] = fmaf(acc[3], inv, ba.w);
    o[4] = fmaf(acc[4], inv, bb.x); o[5] = fmaf(acc[5], inv, bb.y);
    o[6] = fmaf(acc[6], inv, bb.z); o[7] = fmaf(acc[7], inv, bb.w);
    // log_softmax over 64 dims: 8 in-lane + across the 8 q8 lanes (masks 1,2,4)
    float mx = o[0];
    #pragma unroll
    for (int j = 1; j < 8; ++j) mx = fmaxf(mx, o[j]);
    #pragma unroll
    for (int mask = 1; mask < 8; mask <<= 1) mx = fmaxf(mx, __shfl_xor(mx, mask));
    float sm = 0.f;
    #pragma unroll
    for (int j = 0; j < 8; ++j) sm += __expf(o[j] - mx);
    #pragma unroll
    for (int mask = 1; mask < 8; mask <<= 1) sm += __shfl_xor(sm, mask);
    float lse = mx + __logf(sm);
    if (lane < 8) {
        float4 r0, r1;
        r0.x = o[0] - lse; r0.y = o[1] - lse; r0.z = o[2] - lse; r0.w = o[3] - lse;
        r1.x = o[4] - lse; r1.y = o[5] - lse; r1.z = o[6] - lse; r1.w = o[7] - lse;
        *reinterpret_cast<float4*>(&out[(size_t)d * 64 + q8 * 8]) = r0;
        *reinterpret_cast<float4*>(&out[(size_t)d * 64 + q8 * 8 + 4]) = r1;
    }
}

// ---------------- launch ----------------

extern "C" void kernel_launch(void* const* d_in, const int* in_sizes, int n_in,
                              void* d_out, int out_size, void* d_ws, size_t ws_size,
                              hipStream_t stream) {
    const float* x      = (const float*)d_in[0];
    const int*   ei     = (const int*)d_in[1];
    const float* W1     = (const float*)d_in[2];
    const float* a_src1 = (const float*)d_in[3];
    const float* a_dst1 = (const float*)d_in[4];
    const float* b1     = (const float*)d_in[5];
    const float* W2     = (const float*)d_in[6];
    const float* a_src2 = (const float*)d_in[7];
    const float* a_dst2 = (const float*)d_in[8];
    const float* b2     = (const float*)d_in[9];

    int N = in_sizes[0] / 512;
    int E = in_sizes[1] / 2;
    const int* src = ei;
    const int* dst = ei + E;
    int NB = (N + 255) >> NB_SHIFT;          // 391 buckets of 256 nodes

    char* w = (char*)d_ws;
    size_t off = 0;
    auto alloc = [&](size_t bytes) -> void* {
        off = (off + 255) & ~(size_t)255;
        void* p = w + off;
        off += bytes;
        return p;
    };
    int* bcnt   = (int*)alloc((size_t)NB * sizeof(int));
    int* rowptr = (int*)alloc((size_t)(N + 1) * sizeof(int));
    int* bbase  = (int*)alloc((size_t)(NB + 1) * sizeof(int));
    int* bcur   = (int*)alloc((size_t)NB * sizeof(int));
    int* csr    = (int*)alloc((size_t)E * sizeof(int));
    unsigned* pairs = (unsigned*)alloc((size_t)E * sizeof(unsigned));
    unsigned short* hb1 = (unsigned short*)alloc((size_t)N * 64 * sizeof(unsigned short));
    float* as1  = (float*)alloc((size_t)N * 8 * sizeof(float));
    float* ad1  = (float*)alloc((size_t)N * 8 * sizeof(float));
    unsigned short* hb2 = (unsigned short*)alloc((size_t)N * 64 * sizeof(unsigned short));
    float* as2  = (float*)alloc((size_t)N * sizeof(float));
    float* ad2  = (float*)alloc((size_t)N * sizeof(float));

    zero_int_kernel<<<(NB + 255) / 256, 256, 0, stream>>>(bcnt, NB);
    bucket_count_kernel<<<(E + 16383) / 16384, 256, 0, stream>>>(dst, E, bcnt, NB);
    scan_bucket_kernel<<<1, 512, 0, stream>>>(bcnt, NB, bbase, bcur, rowptr, N);
    bucket_scatter_kernel<<<(E + 8191) / 8192, 256, 0, stream>>>(src, dst, E, bcur, pairs, NB);
    build_csr_kernel<<<NB, 512, 0, stream>>>(pairs, bbase, rowptr, csr, N);

    gemm1_kernel<<<(N + 127) / 128, 512, 0, stream>>>(x, W1, a_src1, a_dst1, hb1, as1, ad1, N);
    attn1_kernel<<<(N + 3) / 4, 256, 0, stream>>>(hb1, as1, ad1, rowptr, csr, b1,
                                                  W2, a_src2, a_dst2, hb2, as2, ad2, N);
    attn2_kernel<<<(N + 3) / 4, 256, 0, stream>>>(hb2, as2, ad2, rowptr, csr, b2, (float*)d_out, N);
}

// Round 12
// 389.077 us; speedup vs baseline: 1.0607x; 1.0607x over previous
//
#include <hip/hip_runtime.h>

#define NEG_SLOPE 0.2f
#define NB_SHIFT 8          // bucket = dst >> 8 (256-node windows)
#define LOG2E 1.4426950408889634f

typedef __attribute__((ext_vector_type(8))) short bf16x8;
typedef __attribute__((ext_vector_type(4))) float f32x4;

// bf16 helpers (RNE pack, cheap unpack)
__device__ inline unsigned f2bf(float f) {
    unsigned u = __float_as_uint(f);
    return (u + 0x7fffu + ((u >> 16) & 1u)) >> 16;
}
__device__ inline void bf8up(uint4 u, float* f) {
    f[0] = __uint_as_float(u.x << 16); f[1] = __uint_as_float(u.x & 0xffff0000u);
    f[2] = __uint_as_float(u.y << 16); f[3] = __uint_as_float(u.y & 0xffff0000u);
    f[4] = __uint_as_float(u.z << 16); f[5] = __uint_as_float(u.z & 0xffff0000u);
    f[6] = __uint_as_float(u.w << 16); f[7] = __uint_as_float(u.w & 0xffff0000u);
}
__device__ inline float exp2fast(float x) { return __builtin_amdgcn_exp2f(x); }

// ---------------- CSR build (no per-edge global atomics; packed pairs) ----------------

__global__ void zero_int_kernel(int* __restrict__ p, int n) {
    int i = blockIdx.x * blockDim.x + threadIdx.x;
    if (i < n) p[i] = 0;
}

__global__ __launch_bounds__(256) void bucket_count_kernel(const int* __restrict__ dst, int E,
                                                           int* __restrict__ bcnt, int NB) {
    __shared__ int cnt[512];
    for (int i = threadIdx.x; i < NB; i += 256) cnt[i] = 0;
    __syncthreads();
    int base = blockIdx.x * 16384;
    for (int k = 0; k < 64; ++k) {
        int i = base + k * 256 + threadIdx.x;
        if (i < E) atomicAdd(&cnt[dst[i] >> NB_SHIFT], 1);
    }
    __syncthreads();
    for (int i = threadIdx.x; i < NB; i += 256)
        if (cnt[i]) atomicAdd(&bcnt[i], cnt[i]);
}

__global__ __launch_bounds__(512) void scan_bucket_kernel(const int* __restrict__ bcnt, int nb,
                                                          int* __restrict__ bbase,
                                                          int* __restrict__ bcur,
                                                          int* __restrict__ rowptr, int N) {
    int t = threadIdx.x;
    int v = (t < nb) ? bcnt[t] : 0;
    int s = v;
    #pragma unroll
    for (int d = 1; d < 64; d <<= 1) {
        int o = __shfl_up(s, d);
        if ((t & 63) >= d) s += o;
    }
    __shared__ int ws[8];
    if ((t & 63) == 63) ws[t >> 6] = s;
    __syncthreads();
    int wid = t >> 6;
    int woff = 0;
    for (int w = 0; w < 8; ++w) woff += (w < wid) ? ws[w] : 0;
    int excl = s - v + woff;
    if (t < nb) { bbase[t] = excl; bcur[t] = excl; }
    if (t == 511) { bbase[nb] = excl + v; rowptr[N] = excl + v; }  // grand total = E
}

// scatter packed (src | dstlo<<24) into bucket-grouped storage; 8192 edges/block
__global__ __launch_bounds__(256) void bucket_scatter_kernel(const int* __restrict__ src,
                                                             const int* __restrict__ dst, int E,
                                                             int* __restrict__ bcur,
                                                             unsigned* __restrict__ pairs, int NB) {
    __shared__ int cnt[512];
    __shared__ int base_l[512];
    for (int i = threadIdx.x; i < NB; i += 256) cnt[i] = 0;
    __syncthreads();
    int tbase = blockIdx.x * 8192;
    unsigned e[32];
    int bk[32];
    int rk[32];
    #pragma unroll
    for (int k = 0; k < 32; ++k) {
        int i = tbase + k * 256 + threadIdx.x;
        if (i < E) {
            int dv = dst[i];
            e[k] = (unsigned)src[i] | ((unsigned)(dv & 255) << 24);
            bk[k] = dv >> NB_SHIFT;
            rk[k] = atomicAdd(&cnt[bk[k]], 1);
        } else {
            rk[k] = -1;
        }
    }
    __syncthreads();
    for (int i = threadIdx.x; i < NB; i += 256)
        base_l[i] = cnt[i] ? atomicAdd(&bcur[i], cnt[i]) : 0;
    __syncthreads();
    #pragma unroll
    for (int k = 0; k < 32; ++k)
        if (rk[k] >= 0) pairs[base_l[bk[k]] + rk[k]] = e[k];
}

__global__ __launch_bounds__(512) void build_csr_kernel(const unsigned* __restrict__ pairs,
                                                        const int* __restrict__ bbase,
                                                        int* __restrict__ rowptr,
                                                        int* __restrict__ csr, int N) {
    __shared__ int cnt[256];
    __shared__ int cur[256];
    __shared__ int ws[4];
    int b = blockIdx.x;
    int lo = bbase[b], hi = bbase[b + 1];
    int t = threadIdx.x;
    if (t < 256) cnt[t] = 0;
    __syncthreads();
    for (int j = lo + t; j < hi; j += 512)
        atomicAdd(&cnt[pairs[j] >> 24], 1);
    __syncthreads();
    int v = 0, s = 0;
    if (t < 256) {
        v = cnt[t];
        s = v;
        #pragma unroll
        for (int d = 1; d < 64; d <<= 1) {
            int o = __shfl_up(s, d);
            if ((t & 63) >= d) s += o;
        }
        if ((t & 63) == 63) ws[t >> 6] = s;
    }
    __syncthreads();
    if (t < 256) {
        int wid = t >> 6;
        int woff = 0;
        for (int w2 = 0; w2 < 4; ++w2) woff += (w2 < wid) ? ws[w2] : 0;
        int excl = lo + s - v + woff;
        int node = (b << NB_SHIFT) + t;
        if (node < N) rowptr[node] = excl;
        cur[t] = excl;
    }
    __syncthreads();
    for (int j = lo + t; j < hi; j += 512) {
        unsigned p = pairs[j];
        int pos = atomicAdd(&cur[p >> 24], 1);   // LDS atomic
        csr[pos] = (int)(p & 0x00FFFFFFu);
    }
}

// ---- GEMM1 (MFMA bf16): hb1 = bf16(x @ W1), fused as1/ad1 epilogue ----
// as1/ad1 pre-scaled by LOG2E (attention exps become bare exp2).

__global__ __launch_bounds__(512) void gemm1_kernel(const float* __restrict__ x,
                                                    const float* __restrict__ W,
                                                    const float* __restrict__ a_src,
                                                    const float* __restrict__ a_dst,
                                                    unsigned short* __restrict__ hb1,
                                                    float* __restrict__ as1,
                                                    float* __restrict__ ad1, int N) {
    __shared__ unsigned short Wl[16 * 4 * 64 * 8];   // 64 KB, fragment-ordered
    int tid = threadIdx.x;
    for (int i = tid; i < 512 * 16; i += 512) {
        int k = i >> 4, c4 = (i & 15) * 4;
        float4 v = *reinterpret_cast<const float4*>(&W[(size_t)k * 64 + c4]);
        int ks = k >> 5, kin = k & 31, g = kin >> 3, j = kin & 7;
        float vv[4] = {v.x, v.y, v.z, v.w};
        #pragma unroll
        for (int c = 0; c < 4; ++c) {
            int col = c4 + c;
            int nt = col >> 4, l16 = col & 15;
            Wl[(((ks * 4 + nt) * 64) + g * 16 + l16) * 8 + j] = (unsigned short)f2bf(vv[c]);
        }
    }
    __syncthreads();
    int wave = tid >> 6, lane = tid & 63;
    int m = lane & 15, g = lane >> 4;       // A-row within strip, k-group
    int row0 = blockIdx.x * 128 + wave * 16;
    int arow = row0 + m;
    bool aval = arow < N;
    const float* xr = x + (size_t)(aval ? arow : 0) * 512;
    float asw[4], adw[4];
    #pragma unroll
    for (int nt = 0; nt < 4; ++nt) {
        asw[nt] = a_src[nt * 16 + m] * LOG2E;
        adw[nt] = a_dst[nt * 16 + m] * LOG2E;
    }
    f32x4 acc[4] = {{0.f,0.f,0.f,0.f},{0.f,0.f,0.f,0.f},{0.f,0.f,0.f,0.f},{0.f,0.f,0.f,0.f}};
    for (int ks = 0; ks < 16; ++ks) {
        int ko = ks * 32 + g * 8;
        float4 u0 = make_float4(0.f, 0.f, 0.f, 0.f), u1 = u0;
        if (aval) {
            u0 = *reinterpret_cast<const float4*>(xr + ko);
            u1 = *reinterpret_cast<const float4*>(xr + ko + 4);
        }
        bf16x8 af;
        af[0] = (short)f2bf(u0.x); af[1] = (short)f2bf(u0.y);
        af[2] = (short)f2bf(u0.z); af[3] = (short)f2bf(u0.w);
        af[4] = (short)f2bf(u1.x); af[5] = (short)f2bf(u1.y);
        af[6] = (short)f2bf(u1.z); af[7] = (short)f2bf(u1.w);
        #pragma unroll
        for (int nt = 0; nt < 4; ++nt) {
            bf16x8 bf = *reinterpret_cast<const bf16x8*>(&Wl[((ks * 4 + nt) * 64 + lane) * 8]);
            acc[nt] = __builtin_amdgcn_mfma_f32_16x16x32_bf16(af, bf, acc[nt], 0, 0, 0);
        }
    }
    // D layout: col = lane&15 (=m), row = g*4 + reg  [verified m89]
    #pragma unroll
    for (int r = 0; r < 4; ++r) {
        int orow = row0 + g * 4 + r;
        if (orow < N) {
            #pragma unroll
            for (int nt = 0; nt < 4; ++nt) {
                float dv = acc[nt][r];
                hb1[(size_t)orow * 64 + nt * 16 + m] = (unsigned short)f2bf(dv);
                float pa = dv * asw[nt];
                float pd = dv * adw[nt];
                pa += __shfl_xor(pa, 1); pa += __shfl_xor(pa, 2); pa += __shfl_xor(pa, 4);
                pd += __shfl_xor(pd, 1); pd += __shfl_xor(pd, 2); pd += __shfl_xor(pd, 4);
                if ((m & 7) == 0) {
                    as1[orow * 8 + nt * 2 + (m >> 3)] = pa;
                    ad1[orow * 8 + nt * 2 + (m >> 3)] = pd;
                }
            }
        }
    }
}

// ---- layer-1 attention + FUSED gemm2/alpha2 (grid-stride; W2 staged once/block) ----

__global__ __launch_bounds__(256) void attn1_kernel(
    const unsigned short* __restrict__ hb1, const float* __restrict__ as1,
    const float* __restrict__ ad1, const int* __restrict__ rowptr,
    const int* __restrict__ csr_src, const float* __restrict__ b1,
    const float* __restrict__ W2, const float* __restrict__ a_src2,
    const float* __restrict__ a_dst2, unsigned short* __restrict__ hb2,
    float* __restrict__ as2, float* __restrict__ ad2, int N) {
    __shared__ float Ws[64 * 64];
    __shared__ float asw2[64], adw2[64];
    int tid = threadIdx.x;
    {   // vectorized one-time staging
        const float4* w4 = reinterpret_cast<const float4*>(W2);
        float4* s4 = reinterpret_cast<float4*>(Ws);
        for (int i = tid; i < 1024; i += 256) s4[i] = w4[i];
        if (tid < 64) { asw2[tid] = a_src2[tid] * LOG2E; adw2[tid] = a_dst2[tid] * LOG2E; }
    }
    __syncthreads();
    int wv = tid >> 6;
    int lane = tid & 63;
    int q8 = lane & 7, g = lane >> 3;
    const uint4* hb = reinterpret_cast<const uint4*>(hb1);
    int stride = gridDim.x * 4;
    for (int d = blockIdx.x * 4 + wv; d < N; d += stride) {
        int beg = rowptr[d];
        int edeg = rowptr[d + 1] - beg;
        int tot = edeg + 1;  // + virtual self loop (src = d)
        float adh = ad1[d * 8 + q8];                  // log2-domain
        float es = as1[d * 8 + q8] + adh;             // self score (fixed softmax reference)
        es = fmaxf(es, NEG_SLOPE * es);
        float s = 0.f;
        float acc[8] = {0.f,0.f,0.f,0.f,0.f,0.f,0.f,0.f};
        for (int p0 = 0; p0 < tot; p0 += 8) {
            int p = p0 + g;
            int sn = (p < edeg) ? csr_src[beg + p] : d;
            float e = as1[sn * 8 + q8] + adh;
            e = fmaxf(e, NEG_SLOPE * e);
            float w = (p < tot) ? exp2fast(e - es) : 0.f;
            uint4 u = hb[(size_t)sn * 8 + q8];
            float f[8];
            bf8up(u, f);
            s += w;
            #pragma unroll
            for (int j = 0; j < 8; ++j) acc[j] = fmaf(w, f[j], acc[j]);
        }
        #pragma unroll
        for (int mask = 8; mask < 64; mask <<= 1) {
            s += __shfl_xor(s, mask);
            #pragma unroll
            for (int j = 0; j < 8; ++j) acc[j] += __shfl_xor(acc[j], mask);
        }
        // every lane now holds the reduced octet for head q8 (replicated over g)
        float inv = 1.f / (s + 1e-16f);
        const float4* b4 = reinterpret_cast<const float4*>(b1 + q8 * 8);
        float4 ba = b4[0], bb = b4[1];
        float o[8];
        o[0] = fmaf(acc[0], inv, ba.x); o[1] = fmaf(acc[1], inv, ba.y);
        o[2] = fmaf(acc[2], inv, ba.z); o[3] = fmaf(acc[3], inv, ba.w);
        o[4] = fmaf(acc[4], inv, bb.x); o[5] = fmaf(acc[5], inv, bb.y);
        o[6] = fmaf(acc[6], inv, bb.z); o[7] = fmaf(acc[7], inv, bb.w);
        #pragma unroll
        for (int j = 0; j < 8; ++j) o[j] = (o[j] > 0.f) ? o[j] : (__expf(o[j]) - 1.f);
        // fused gemm2: lane -> output dim `lane`; helu[c*8+i] = shfl(o[i], c)
        float h2v = 0.f;
        #pragma unroll
        for (int c = 0; c < 8; ++c) {
            #pragma unroll
            for (int i = 0; i < 8; ++i) {
                float hv = __shfl(o[i], c);
                h2v = fmaf(hv, Ws[(c * 8 + i) * 64 + lane], h2v);
            }
        }
        hb2[(size_t)d * 64 + lane] = (unsigned short)f2bf(h2v);
        float pa = h2v * asw2[lane];
        float pb = h2v * adw2[lane];
        #pragma unroll
        for (int mask = 1; mask < 64; mask <<= 1) {
            pa += __shfl_xor(pa, mask);
            pb += __shfl_xor(pb, mask);
        }
        if (lane == 0) { as2[d] = pa; ad2[d] = pb; }
    }
}

// ---- layer-2 attention + log_softmax: fixed-reference softmax, 8 lanes/edge ----

__global__ __launch_bounds__(256) void attn2_kernel(
    const unsigned short* __restrict__ hb2, const float* __restrict__ as2,
    const float* __restrict__ ad2, const int* __restrict__ rowptr,
    const int* __restrict__ csr_src, const float* __restrict__ b2,
    float* __restrict__ out, int N) {
    int wv = threadIdx.x >> 6;
    int lane = threadIdx.x & 63;
    int d = blockIdx.x * 4 + wv;
    if (d >= N) return;
    int beg = rowptr[d];
    int edeg = rowptr[d + 1] - beg;
    int tot = edeg + 1;
    int q8 = lane & 7, g = lane >> 3;
    float add = ad2[d];                           // log2-domain
    float es = as2[d] + add;
    es = fmaxf(es, NEG_SLOPE * es);
    const uint4* hb = reinterpret_cast<const uint4*>(hb2);
    float s = 0.f;
    float acc[8] = {0.f,0.f,0.f,0.f,0.f,0.f,0.f,0.f};
    for (int p0 = 0; p0 < tot; p0 += 8) {
        int p = p0 + g;
        int sn = (p < edeg) ? csr_src[beg + p] : d;
        float e = as2[sn] + add;
        e = fmaxf(e, NEG_SLOPE * e);
        float w = (p < tot) ? exp2fast(e - es) : 0.f;
        uint4 u = hb[(size_t)sn * 8 + q8];
        float f[8];
        bf8up(u, f);
        s += w;
        #pragma unroll
        for (int j = 0; j < 8; ++j) acc[j] = fmaf(w, f[j], acc[j]);
    }
    #pragma unroll
    for (int mask = 8; mask < 64; mask <<= 1) {
        s += __shfl_xor(s, mask);
        #pragma unroll
        for (int j = 0; j < 8; ++j) acc[j] += __shfl_xor(acc[j], mask);
    }
    // all lanes hold full s / acc (xor-reduce broadcasts)
    float inv = 1.f / (s + 1e-16f);
    const float4* b4 = reinterpret_cast<const float4*>(b2 + q8 * 8);
    float4 ba = b4[0], bb = b4[1];
    float o[8];
    o[0] = fmaf(acc[0], inv, ba.x); o[1] = fmaf(acc[1], inv, ba.y);
    o[2] = fmaf(acc[2], inv, ba.z); o[3] = fmaf(acc[3], inv, ba.w);
    o[4] = fmaf(acc[4], inv, bb.x); o[5] = fmaf(acc[5], inv, bb.y);
    o[6] = fmaf(acc[6], inv, bb.z); o[7] = fmaf(acc[7], inv, bb.w);
    // log_softmax over 64 dims: 8 in-lane + across the 8 q8 lanes (masks 1,2,4)
    float mx = o[0];
    #pragma unroll
    for (int j = 1; j < 8; ++j) mx = fmaxf(mx, o[j]);
    #pragma unroll
    for (int mask = 1; mask < 8; mask <<= 1) mx = fmaxf(mx, __shfl_xor(mx, mask));
    float sm = 0.f;
    #pragma unroll
    for (int j = 0; j < 8; ++j) sm += __expf(o[j] - mx);
    #pragma unroll
    for (int mask = 1; mask < 8; mask <<= 1) sm += __shfl_xor(sm, mask);
    float lse = mx + __logf(sm);
    if (lane < 8) {
        float4 r0, r1;
        r0.x = o[0] - lse; r0.y = o[1] - lse; r0.z = o[2] - lse; r0.w = o[3] - lse;
        r1.x = o[4] - lse; r1.y = o[5] - lse; r1.z = o[6] - lse; r1.w = o[7] - lse;
        *reinterpret_cast<float4*>(&out[(size_t)d * 64 + q8 * 8]) = r0;
        *reinterpret_cast<float4*>(&out[(size_t)d * 64 + q8 * 8 + 4]) = r1;
    }
}

// ---------------- launch ----------------

extern "C" void kernel_launch(void* const* d_in, const int* in_sizes, int n_in,
                              void* d_out, int out_size, void* d_ws, size_t ws_size,
                              hipStream_t stream) {
    const float* x      = (const float*)d_in[0];
    const int*   ei     = (const int*)d_in[1];
    const float* W1     = (const float*)d_in[2];
    const float* a_src1 = (const float*)d_in[3];
    const float* a_dst1 = (const float*)d_in[4];
    const float* b1     = (const float*)d_in[5];
    const float* W2     = (const float*)d_in[6];
    const float* a_src2 = (const float*)d_in[7];
    const float* a_dst2 = (const float*)d_in[8];
    const float* b2     = (const float*)d_in[9];

    int N = in_sizes[0] / 512;
    int E = in_sizes[1] / 2;
    const int* src = ei;
    const int* dst = ei + E;
    int NB = (N + 255) >> NB_SHIFT;          // 391 buckets of 256 nodes

    char* w = (char*)d_ws;
    size_t off = 0;
    auto alloc = [&](size_t bytes) -> void* {
        off = (off + 255) & ~(size_t)255;
        void* p = w + off;
        off += bytes;
        return p;
    };
    int* bcnt   = (int*)alloc((size_t)NB * sizeof(int));
    int* rowptr = (int*)alloc((size_t)(N + 1) * sizeof(int));
    int* bbase  = (int*)alloc((size_t)(NB + 1) * sizeof(int));
    int* bcur   = (int*)alloc((size_t)NB * sizeof(int));
    int* csr    = (int*)alloc((size_t)E * sizeof(int));
    unsigned* pairs = (unsigned*)alloc((size_t)E * sizeof(unsigned));
    unsigned short* hb1 = (unsigned short*)alloc((size_t)N * 64 * sizeof(unsigned short));
    float* as1  = (float*)alloc((size_t)N * 8 * sizeof(float));
    float* ad1  = (float*)alloc((size_t)N * 8 * sizeof(float));
    unsigned short* hb2 = (unsigned short*)alloc((size_t)N * 64 * sizeof(unsigned short));
    float* as2  = (float*)alloc((size_t)N * sizeof(float));
    float* ad2  = (float*)alloc((size_t)N * sizeof(float));

    zero_int_kernel<<<(NB + 255) / 256, 256, 0, stream>>>(bcnt, NB);
    bucket_count_kernel<<<(E + 16383) / 16384, 256, 0, stream>>>(dst, E, bcnt, NB);
    scan_bucket_kernel<<<1, 512, 0, stream>>>(bcnt, NB, bbase, bcur, rowptr, N);
    bucket_scatter_kernel<<<(E + 8191) / 8192, 256, 0, stream>>>(src, dst, E, bcur, pairs, NB);
    build_csr_kernel<<<NB, 512, 0, stream>>>(pairs, bbase, rowptr, csr, N);

    gemm1_kernel<<<(N + 127) / 128, 512, 0, stream>>>(x, W1, a_src1, a_dst1, hb1, as1, ad1, N);
    attn1_kernel<<<2048, 256, 0, stream>>>(hb1, as1, ad1, rowptr, csr, b1,
                                           W2, a_src2, a_dst2, hb2, as2, ad2, N);
    attn2_kernel<<<(N + 3) / 4, 256, 0, stream>>>(hb2, as2, ad2, rowptr, csr, b2, (float*)d_out, N);
}

// Round 13
// 355.731 us; speedup vs baseline: 1.1601x; 1.0937x over previous
//
#include <hip/hip_runtime.h>

#define NEG_SLOPE 0.2f
#define NB_SHIFT 8          // bucket = dst >> 8 (256-node windows)
#define LOG2E 1.4426950408889634f

typedef __attribute__((ext_vector_type(8))) short bf16x8;
typedef __attribute__((ext_vector_type(4))) float f32x4;

// bf16 helpers (RNE pack, cheap unpack)
__device__ inline unsigned f2bf(float f) {
    unsigned u = __float_as_uint(f);
    return (u + 0x7fffu + ((u >> 16) & 1u)) >> 16;
}
__device__ inline void bf8up(uint4 u, float* f) {
    f[0] = __uint_as_float(u.x << 16); f[1] = __uint_as_float(u.x & 0xffff0000u);
    f[2] = __uint_as_float(u.y << 16); f[3] = __uint_as_float(u.y & 0xffff0000u);
    f[4] = __uint_as_float(u.z << 16); f[5] = __uint_as_float(u.z & 0xffff0000u);
    f[6] = __uint_as_float(u.w << 16); f[7] = __uint_as_float(u.w & 0xffff0000u);
}
__device__ inline float exp2fast(float x) { return __builtin_amdgcn_exp2f(x); }

// ---------------- CSR build (no per-edge global atomics; packed pairs) ----------------

__global__ void zero_int_kernel(int* __restrict__ p, int n) {
    int i = blockIdx.x * blockDim.x + threadIdx.x;
    if (i < n) p[i] = 0;
}

__global__ __launch_bounds__(256) void bucket_count_kernel(const int* __restrict__ dst, int E,
                                                           int* __restrict__ bcnt, int NB) {
    __shared__ int cnt[512];
    for (int i = threadIdx.x; i < NB; i += 256) cnt[i] = 0;
    __syncthreads();
    int base = blockIdx.x * 16384;
    for (int k = 0; k < 64; ++k) {
        int i = base + k * 256 + threadIdx.x;
        if (i < E) atomicAdd(&cnt[dst[i] >> NB_SHIFT], 1);
    }
    __syncthreads();
    for (int i = threadIdx.x; i < NB; i += 256)
        if (cnt[i]) atomicAdd(&bcnt[i], cnt[i]);
}

__global__ __launch_bounds__(512) void scan_bucket_kernel(const int* __restrict__ bcnt, int nb,
                                                          int* __restrict__ bbase,
                                                          int* __restrict__ bcur,
                                                          int* __restrict__ rowptr, int N) {
    int t = threadIdx.x;
    int v = (t < nb) ? bcnt[t] : 0;
    int s = v;
    #pragma unroll
    for (int d = 1; d < 64; d <<= 1) {
        int o = __shfl_up(s, d);
        if ((t & 63) >= d) s += o;
    }
    __shared__ int ws[8];
    if ((t & 63) == 63) ws[t >> 6] = s;
    __syncthreads();
    int wid = t >> 6;
    int woff = 0;
    for (int w = 0; w < 8; ++w) woff += (w < wid) ? ws[w] : 0;
    int excl = s - v + woff;
    if (t < nb) { bbase[t] = excl; bcur[t] = excl; }
    if (t == 511) { bbase[nb] = excl + v; rowptr[N] = excl + v; }  // grand total = E
}

// scatter packed (src | dstlo<<24) into bucket-grouped storage; 8192 edges/block
__global__ __launch_bounds__(256) void bucket_scatter_kernel(const int* __restrict__ src,
                                                             const int* __restrict__ dst, int E,
                                                             int* __restrict__ bcur,
                                                             unsigned* __restrict__ pairs, int NB) {
    __shared__ int cnt[512];
    __shared__ int base_l[512];
    for (int i = threadIdx.x; i < NB; i += 256) cnt[i] = 0;
    __syncthreads();
    int tbase = blockIdx.x * 8192;
    unsigned e[32];
    int bk[32];
    int rk[32];
    #pragma unroll
    for (int k = 0; k < 32; ++k) {
        int i = tbase + k * 256 + threadIdx.x;
        if (i < E) {
            int dv = dst[i];
            e[k] = (unsigned)src[i] | ((unsigned)(dv & 255) << 24);
            bk[k] = dv >> NB_SHIFT;
            rk[k] = atomicAdd(&cnt[bk[k]], 1);
        } else {
            rk[k] = -1;
        }
    }
    __syncthreads();
    for (int i = threadIdx.x; i < NB; i += 256)
        base_l[i] = cnt[i] ? atomicAdd(&bcur[i], cnt[i]) : 0;
    __syncthreads();
    #pragma unroll
    for (int k = 0; k < 32; ++k)
        if (rk[k] >= 0) pairs[base_l[bk[k]] + rk[k]] = e[k];
}

__global__ __launch_bounds__(512) void build_csr_kernel(const unsigned* __restrict__ pairs,
                                                        const int* __restrict__ bbase,
                                                        int* __restrict__ rowptr,
                                                        int* __restrict__ csr, int N) {
    __shared__ int cnt[256];
    __shared__ int cur[256];
    __shared__ int ws[4];
    int b = blockIdx.x;
    int lo = bbase[b], hi = bbase[b + 1];
    int t = threadIdx.x;
    if (t < 256) cnt[t] = 0;
    __syncthreads();
    for (int j = lo + t; j < hi; j += 512)
        atomicAdd(&cnt[pairs[j] >> 24], 1);
    __syncthreads();
    int v = 0, s = 0;
    if (t < 256) {
        v = cnt[t];
        s = v;
        #pragma unroll
        for (int d = 1; d < 64; d <<= 1) {
            int o = __shfl_up(s, d);
            if ((t & 63) >= d) s += o;
        }
        if ((t & 63) == 63) ws[t >> 6] = s;
    }
    __syncthreads();
    if (t < 256) {
        int wid = t >> 6;
        int woff = 0;
        for (int w2 = 0; w2 < 4; ++w2) woff += (w2 < wid) ? ws[w2] : 0;
        int excl = lo + s - v + woff;
        int node = (b << NB_SHIFT) + t;
        if (node < N) rowptr[node] = excl;
        cur[t] = excl;
    }
    __syncthreads();
    for (int j = lo + t; j < hi; j += 512) {
        unsigned p = pairs[j];
        int pos = atomicAdd(&cur[p >> 24], 1);   // LDS atomic
        csr[pos] = (int)(p & 0x00FFFFFFu);
    }
}

// ---- GEMM1 (MFMA bf16): hb1 = bf16(x @ W1), fused as1/ad1 epilogue ----
// as1/ad1 pre-scaled by LOG2E (attention exps become bare exp2).

__global__ __launch_bounds__(512) void gemm1_kernel(const float* __restrict__ x,
                                                    const float* __restrict__ W,
                                                    const float* __restrict__ a_src,
                                                    const float* __restrict__ a_dst,
                                                    unsigned short* __restrict__ hb1,
                                                    float* __restrict__ as1,
                                                    float* __restrict__ ad1, int N) {
    __shared__ unsigned short Wl[16 * 4 * 64 * 8];   // 64 KB, fragment-ordered
    int tid = threadIdx.x;
    for (int i = tid; i < 512 * 16; i += 512) {
        int k = i >> 4, c4 = (i & 15) * 4;
        float4 v = *reinterpret_cast<const float4*>(&W[(size_t)k * 64 + c4]);
        int ks = k >> 5, kin = k & 31, g = kin >> 3, j = kin & 7;
        float vv[4] = {v.x, v.y, v.z, v.w};
        #pragma unroll
        for (int c = 0; c < 4; ++c) {
            int col = c4 + c;
            int nt = col >> 4, l16 = col & 15;
            Wl[(((ks * 4 + nt) * 64) + g * 16 + l16) * 8 + j] = (unsigned short)f2bf(vv[c]);
        }
    }
    __syncthreads();
    int wave = tid >> 6, lane = tid & 63;
    int m = lane & 15, g = lane >> 4;       // A-row within strip, k-group
    int row0 = blockIdx.x * 128 + wave * 16;
    int arow = row0 + m;
    bool aval = arow < N;
    const float* xr = x + (size_t)(aval ? arow : 0) * 512;
    float asw[4], adw[4];
    #pragma unroll
    for (int nt = 0; nt < 4; ++nt) {
        asw[nt] = a_src[nt * 16 + m] * LOG2E;
        adw[nt] = a_dst[nt * 16 + m] * LOG2E;
    }
    f32x4 acc[4] = {{0.f,0.f,0.f,0.f},{0.f,0.f,0.f,0.f},{0.f,0.f,0.f,0.f},{0.f,0.f,0.f,0.f}};
    for (int ks = 0; ks < 16; ++ks) {
        int ko = ks * 32 + g * 8;
        float4 u0 = make_float4(0.f, 0.f, 0.f, 0.f), u1 = u0;
        if (aval) {
            u0 = *reinterpret_cast<const float4*>(xr + ko);
            u1 = *reinterpret_cast<const float4*>(xr + ko + 4);
        }
        bf16x8 af;
        af[0] = (short)f2bf(u0.x); af[1] = (short)f2bf(u0.y);
        af[2] = (short)f2bf(u0.z); af[3] = (short)f2bf(u0.w);
        af[4] = (short)f2bf(u1.x); af[5] = (short)f2bf(u1.y);
        af[6] = (short)f2bf(u1.z); af[7] = (short)f2bf(u1.w);
        #pragma unroll
        for (int nt = 0; nt < 4; ++nt) {
            bf16x8 bf = *reinterpret_cast<const bf16x8*>(&Wl[((ks * 4 + nt) * 64 + lane) * 8]);
            acc[nt] = __builtin_amdgcn_mfma_f32_16x16x32_bf16(af, bf, acc[nt], 0, 0, 0);
        }
    }
    // D layout: col = lane&15 (=m), row = g*4 + reg  [verified m89]
    #pragma unroll
    for (int r = 0; r < 4; ++r) {
        int orow = row0 + g * 4 + r;
        if (orow < N) {
            #pragma unroll
            for (int nt = 0; nt < 4; ++nt) {
                float dv = acc[nt][r];
                hb1[(size_t)orow * 64 + nt * 16 + m] = (unsigned short)f2bf(dv);
                float pa = dv * asw[nt];
                float pd = dv * adw[nt];
                pa += __shfl_xor(pa, 1); pa += __shfl_xor(pa, 2); pa += __shfl_xor(pa, 4);
                pd += __shfl_xor(pd, 1); pd += __shfl_xor(pd, 2); pd += __shfl_xor(pd, 4);
                if ((m & 7) == 0) {
                    as1[orow * 8 + nt * 2 + (m >> 3)] = pa;
                    ad1[orow * 8 + nt * 2 + (m >> 3)] = pd;
                }
            }
        }
    }
}

// ---- layer-1 attention + FUSED gemm2/alpha2 (grid-stride; W2 staged once/block).
// Inner gather loop software-pipelined 2-deep: csr load 2 iters ahead,
// value loads (as1/hb) 1 iter ahead. OOB slots read node d's own row (w=0). ----

__global__ __launch_bounds__(256) void attn1_kernel(
    const unsigned short* __restrict__ hb1, const float* __restrict__ as1,
    const float* __restrict__ ad1, const int* __restrict__ rowptr,
    const int* __restrict__ csr_src, const float* __restrict__ b1,
    const float* __restrict__ W2, const float* __restrict__ a_src2,
    const float* __restrict__ a_dst2, unsigned short* __restrict__ hb2,
    float* __restrict__ as2, float* __restrict__ ad2, int N) {
    __shared__ float Ws[64 * 64];
    __shared__ float asw2[64], adw2[64];
    int tid = threadIdx.x;
    {   // vectorized one-time staging
        const float4* w4 = reinterpret_cast<const float4*>(W2);
        float4* s4 = reinterpret_cast<float4*>(Ws);
        for (int i = tid; i < 1024; i += 256) s4[i] = w4[i];
        if (tid < 64) { asw2[tid] = a_src2[tid] * LOG2E; adw2[tid] = a_dst2[tid] * LOG2E; }
    }
    __syncthreads();
    int wv = tid >> 6;
    int lane = tid & 63;
    int q8 = lane & 7, g = lane >> 3;
    const uint4* hb = reinterpret_cast<const uint4*>(hb1);
    int stride = gridDim.x * 4;
    for (int d = blockIdx.x * 4 + wv; d < N; d += stride) {
        int beg = rowptr[d];
        int edeg = rowptr[d + 1] - beg;
        int tot = edeg + 1;  // + virtual self loop (src = d)
        float adh = ad1[d * 8 + q8];                  // log2-domain
        float es = as1[d * 8 + q8] + adh;             // self score (fixed softmax reference)
        es = fmaxf(es, NEG_SLOPE * es);
        float s = 0.f;
        float acc[8] = {0.f,0.f,0.f,0.f,0.f,0.f,0.f,0.f};
        int iters = (tot + 7) >> 3;
        // pipeline prologue
        int p = g;
        int sn_c = (p < edeg) ? csr_src[beg + p] : d;
        float ea_c = as1[sn_c * 8 + q8];
        uint4 u_c = hb[(size_t)sn_c * 8 + q8];
        int pn = p + 8;
        int sn_n = (pn < edeg) ? csr_src[beg + pn] : d;
        for (int it = 0; it < iters; ++it) {
            // issue next-iter value loads + next-next csr load (all independent of compute)
            float ea_n = as1[sn_n * 8 + q8];
            uint4 u_n = hb[(size_t)sn_n * 8 + q8];
            int pn2 = pn + 8;
            int sn_n2 = (pn2 < edeg) ? csr_src[beg + pn2] : d;
            // compute current (values loaded last iteration)
            float e = ea_c + adh;
            e = fmaxf(e, NEG_SLOPE * e);
            float w = (p < tot) ? exp2fast(e - es) : 0.f;
            float f[8];
            bf8up(u_c, f);
            s += w;
            #pragma unroll
            for (int j = 0; j < 8; ++j) acc[j] = fmaf(w, f[j], acc[j]);
            // shift pipeline
            p = pn; pn = pn2; sn_n = sn_n2;
            ea_c = ea_n; u_c = u_n;
        }
        #pragma unroll
        for (int mask = 8; mask < 64; mask <<= 1) {
            s += __shfl_xor(s, mask);
            #pragma unroll
            for (int j = 0; j < 8; ++j) acc[j] += __shfl_xor(acc[j], mask);
        }
        // every lane now holds the reduced octet for head q8 (replicated over g)
        float inv = 1.f / (s + 1e-16f);
        const float4* b4 = reinterpret_cast<const float4*>(b1 + q8 * 8);
        float4 ba = b4[0], bb = b4[1];
        float o[8];
        o[0] = fmaf(acc[0], inv, ba.x); o[1] = fmaf(acc[1], inv, ba.y);
        o[2] = fmaf(acc[2], inv, ba.z); o[3] = fmaf(acc[3], inv, ba.w);
        o[4] = fmaf(acc[4], inv, bb.x); o[5] = fmaf(acc[5], inv, bb.y);
        o[6] = fmaf(acc[6], inv, bb.z); o[7] = fmaf(acc[7], inv, bb.w);
        #pragma unroll
        for (int j = 0; j < 8; ++j) o[j] = (o[j] > 0.f) ? o[j] : (__expf(o[j]) - 1.f);
        // fused gemm2: lane -> output dim `lane`; helu[c*8+i] = shfl(o[i], c)
        float h2v = 0.f;
        #pragma unroll
        for (int c = 0; c < 8; ++c) {
            #pragma unroll
            for (int i = 0; i < 8; ++i) {
                float hv = __shfl(o[i], c);
                h2v = fmaf(hv, Ws[(c * 8 + i) * 64 + lane], h2v);
            }
        }
        hb2[(size_t)d * 64 + lane] = (unsigned short)f2bf(h2v);
        float pa = h2v * asw2[lane];
        float pb = h2v * adw2[lane];
        #pragma unroll
        for (int mask = 1; mask < 64; mask <<= 1) {
            pa += __shfl_xor(pa, mask);
            pb += __shfl_xor(pb, mask);
        }
        if (lane == 0) { as2[d] = pa; ad2[d] = pb; }
    }
}

// ---- layer-2 attention + log_softmax: fixed-reference softmax, 8 lanes/edge,
// software-pipelined gather loop ----

__global__ __launch_bounds__(256) void attn2_kernel(
    const unsigned short* __restrict__ hb2, const float* __restrict__ as2,
    const float* __restrict__ ad2, const int* __restrict__ rowptr,
    const int* __restrict__ csr_src, const float* __restrict__ b2,
    float* __restrict__ out, int N) {
    int wv = threadIdx.x >> 6;
    int lane = threadIdx.x & 63;
    int d = blockIdx.x * 4 + wv;
    if (d >= N) return;
    int beg = rowptr[d];
    int edeg = rowptr[d + 1] - beg;
    int tot = edeg + 1;
    int q8 = lane & 7, g = lane >> 3;
    float add = ad2[d];                           // log2-domain
    float es = as2[d] + add;
    es = fmaxf(es, NEG_SLOPE * es);
    const uint4* hb = reinterpret_cast<const uint4*>(hb2);
    float s = 0.f;
    float acc[8] = {0.f,0.f,0.f,0.f,0.f,0.f,0.f,0.f};
    int iters = (tot + 7) >> 3;
    int p = g;
    int sn_c = (p < edeg) ? csr_src[beg + p] : d;
    float ea_c = as2[sn_c];
    uint4 u_c = hb[(size_t)sn_c * 8 + q8];
    int pn = p + 8;
    int sn_n = (pn < edeg) ? csr_src[beg + pn] : d;
    for (int it = 0; it < iters; ++it) {
        float ea_n = as2[sn_n];
        uint4 u_n = hb[(size_t)sn_n * 8 + q8];
        int pn2 = pn + 8;
        int sn_n2 = (pn2 < edeg) ? csr_src[beg + pn2] : d;
        float e = ea_c + add;
        e = fmaxf(e, NEG_SLOPE * e);
        float w = (p < tot) ? exp2fast(e - es) : 0.f;
        float f[8];
        bf8up(u_c, f);
        s += w;
        #pragma unroll
        for (int j = 0; j < 8; ++j) acc[j] = fmaf(w, f[j], acc[j]);
        p = pn; pn = pn2; sn_n = sn_n2;
        ea_c = ea_n; u_c = u_n;
    }
    #pragma unroll
    for (int mask = 8; mask < 64; mask <<= 1) {
        s += __shfl_xor(s, mask);
        #pragma unroll
        for (int j = 0; j < 8; ++j) acc[j] += __shfl_xor(acc[j], mask);
    }
    // all lanes hold full s / acc (xor-reduce broadcasts)
    float inv = 1.f / (s + 1e-16f);
    const float4* b4 = reinterpret_cast<const float4*>(b2 + q8 * 8);
    float4 ba = b4[0], bb = b4[1];
    float o[8];
    o[0] = fmaf(acc[0], inv, ba.x); o[1] = fmaf(acc[1], inv, ba.y);
    o[2] = fmaf(acc[2], inv, ba.z); o[3] = fmaf(acc[3], inv, ba.w);
    o[4] = fmaf(acc[4], inv, bb.x); o[5] = fmaf(acc[5], inv, bb.y);
    o[6] = fmaf(acc[6], inv, bb.z); o[7] = fmaf(acc[7], inv, bb.w);
    // log_softmax over 64 dims: 8 in-lane + across the 8 q8 lanes (masks 1,2,4)
    float mx = o[0];
    #pragma unroll
    for (int j = 1; j < 8; ++j) mx = fmaxf(mx, o[j]);
    #pragma unroll
    for (int mask = 1; mask < 8; mask <<= 1) mx = fmaxf(mx, __shfl_xor(mx, mask));
    float sm = 0.f;
    #pragma unroll
    for (int j = 0; j < 8; ++j) sm += __expf(o[j] - mx);
    #pragma unroll
    for (int mask = 1; mask < 8; mask <<= 1) sm += __shfl_xor(sm, mask);
    float lse = mx + __logf(sm);
    if (lane < 8) {
        float4 r0, r1;
        r0.x = o[0] - lse; r0.y = o[1] - lse; r0.z = o[2] - lse; r0.w = o[3] - lse;
        r1.x = o[4] - lse; r1.y = o[5] - lse; r1.z = o[6] - lse; r1.w = o[7] - lse;
        *reinterpret_cast<float4*>(&out[(size_t)d * 64 + q8 * 8]) = r0;
        *reinterpret_cast<float4*>(&out[(size_t)d * 64 + q8 * 8 + 4]) = r1;
    }
}

// ---------------- launch ----------------

extern "C" void kernel_launch(void* const* d_in, const int* in_sizes, int n_in,
                              void* d_out, int out_size, void* d_ws, size_t ws_size,
                              hipStream_t stream) {
    const float* x      = (const float*)d_in[0];
    const int*   ei     = (const int*)d_in[1];
    const float* W1     = (const float*)d_in[2];
    const float* a_src1 = (const float*)d_in[3];
    const float* a_dst1 = (const float*)d_in[4];
    const float* b1     = (const float*)d_in[5];
    const float* W2     = (const float*)d_in[6];
    const float* a_src2 = (const float*)d_in[7];
    const float* a_dst2 = (const float*)d_in[8];
    const float* b2     = (const float*)d_in[9];

    int N = in_sizes[0] / 512;
    int E = in_sizes[1] / 2;
    const int* src = ei;
    const int* dst = ei + E;
    int NB = (N + 255) >> NB_SHIFT;          // 391 buckets of 256 nodes

    char* w = (char*)d_ws;
    size_t off = 0;
    auto alloc = [&](size_t bytes) -> void* {
        off = (off + 255) & ~(size_t)255;
        void* p = w + off;
        off += bytes;
        return p;
    };
    int* bcnt   = (int*)alloc((size_t)NB * sizeof(int));
    int* rowptr = (int*)alloc((size_t)(N + 1) * sizeof(int));
    int* bbase  = (int*)alloc((size_t)(NB + 1) * sizeof(int));
    int* bcur   = (int*)alloc((size_t)NB * sizeof(int));
    int* csr    = (int*)alloc((size_t)E * sizeof(int));
    unsigned* pairs = (unsigned*)alloc((size_t)E * sizeof(unsigned));
    unsigned short* hb1 = (unsigned short*)alloc((size_t)N * 64 * sizeof(unsigned short));
    float* as1  = (float*)alloc((size_t)N * 8 * sizeof(float));
    float* ad1  = (float*)alloc((size_t)N * 8 * sizeof(float));
    unsigned short* hb2 = (unsigned short*)alloc((size_t)N * 64 * sizeof(unsigned short));
    float* as2  = (float*)alloc((size_t)N * sizeof(float));
    float* ad2  = (float*)alloc((size_t)N * sizeof(float));

    zero_int_kernel<<<(NB + 255) / 256, 256, 0, stream>>>(bcnt, NB);
    bucket_count_kernel<<<(E + 16383) / 16384, 256, 0, stream>>>(dst, E, bcnt, NB);
    scan_bucket_kernel<<<1, 512, 0, stream>>>(bcnt, NB, bbase, bcur, rowptr, N);
    bucket_scatter_kernel<<<(E + 8191) / 8192, 256, 0, stream>>>(src, dst, E, bcur, pairs, NB);
    build_csr_kernel<<<NB, 512, 0, stream>>>(pairs, bbase, rowptr, csr, N);

    gemm1_kernel<<<(N + 127) / 128, 512, 0, stream>>>(x, W1, a_src1, a_dst1, hb1, as1, ad1, N);
    attn1_kernel<<<2048, 256, 0, stream>>>(hb1, as1, ad1, rowptr, csr, b1,
                                           W2, a_src2, a_dst2, hb2, as2, ad2, N);
    attn2_kernel<<<(N + 3) / 4, 256, 0, stream>>>(hb2, as2, ad2, rowptr, csr, b2, (float*)d_out, N);
}